// Round 8
// baseline (287.689 us; speedup 1.0000x reference)
//
#include <hip/hip_runtime.h>
#include <hip/hip_bf16.h>

#define T_NUM 8192
#define D_DIM 1024
#define O_DIM 1024
#define E_NUM 8
#define CAP   8192
#define BM 256
#define BN 256
#define BK 64
#define NT (D_DIM / BK)   // 16 K-tiles

typedef float  f32x4  __attribute__((ext_vector_type(4)));
typedef __bf16 bf16x8 __attribute__((ext_vector_type(8)));

__device__ __forceinline__ void gld_lds16(const void* g, void* l) {
  __builtin_amdgcn_global_load_lds(
      (__attribute__((address_space(1))) void*)(void*)(g),
      (__attribute__((address_space(3))) void*)(l), 16, 0, 0);
}

__device__ __forceinline__ unsigned short f2bf(float f) {
  __hip_bfloat16 h = __float2bfloat16(f);
  return __builtin_bit_cast(unsigned short, h);
}

// ---------------- fp32 -> bf16 conversion (for We) ----------------
__global__ __launch_bounds__(256) void cvt_kernel(const float* __restrict__ in,
                                                  ushort* __restrict__ out, int n4) {
  int i = blockIdx.x * 256 + threadIdx.x;
  if (i >= n4) return;
  float4 v = ((const float4*)in)[i];
  ushort4 r;
  r.x = f2bf(v.x); r.y = f2bf(v.y); r.z = f2bf(v.z); r.w = f2bf(v.w);
  ((ushort4*)out)[i] = r;
}

// ---------------- gating: logits, top-2, softmax, hierarchical scatter ----
__global__ __launch_bounds__(256) void gate_kernel(const float* __restrict__ x,
                                                   const float* __restrict__ Wg,
                                                   ushort* __restrict__ xb,
                                                   int* __restrict__ counts,
                                                   int* __restrict__ perm,
                                                   float* __restrict__ wgt) {
  __shared__ int   s_sel[64][2];
  __shared__ float s_w[64][2];
  __shared__ int   s_hist[E_NUM];
  __shared__ int   s_cursor[E_NUM];

  int tid  = threadIdx.x;
  int lane = tid & 63;
  int wv   = tid >> 6;
  if (tid < E_NUM) s_hist[tid] = 0;

  int t0 = blockIdx.x * 64;

  for (int it = 0; it < 16; ++it) {
    int tl = wv * 16 + it;
    int t  = t0 + tl;
    const float4* xv = (const float4*)(x + (long)t * D_DIM);
    ushort4* xo = (ushort4*)(xb + (long)t * D_DIM);

    float acc[E_NUM];
#pragma unroll
    for (int e = 0; e < E_NUM; ++e) acc[e] = 0.f;

#pragma unroll
    for (int i = 0; i < 4; ++i) {
      float4 xf = xv[lane + i * 64];
      ushort4 r;
      r.x = f2bf(xf.x); r.y = f2bf(xf.y); r.z = f2bf(xf.z); r.w = f2bf(xf.w);
      xo[lane + i * 64] = r;
#pragma unroll
      for (int e = 0; e < E_NUM; ++e) {
        const float4* wv4 = (const float4*)(Wg + e * D_DIM);
        float4 wf = wv4[lane + i * 64];
        acc[e] += xf.x * wf.x + xf.y * wf.y + xf.z * wf.z + xf.w * wf.w;
      }
    }

    float logit[E_NUM];
#pragma unroll
    for (int e = 0; e < E_NUM; ++e) {
      float v = acc[e];
      for (int off = 32; off > 0; off >>= 1) v += __shfl_down(v, off);
      logit[e] = v;                      // valid on lane 0
    }

    if (lane == 0) {
      int e0 = 0; float v0 = logit[0];
#pragma unroll
      for (int e = 1; e < E_NUM; ++e)
        if (logit[e] > v0) { v0 = logit[e]; e0 = e; }  // strict > : lowest idx wins
      int e1 = -1; float v1 = -1e30f;
#pragma unroll
      for (int e = 0; e < E_NUM; ++e) {
        if (e == e0) continue;
        if (logit[e] > v1) { v1 = logit[e]; e1 = e; }
      }
      float ex  = expf(v1 - v0);
      float den = 1.f + ex;
      s_sel[tl][0] = e0; s_w[tl][0] = 1.f / den;
      s_sel[tl][1] = e1; s_w[tl][1] = ex / den;
    }
  }
  __syncthreads();

  if (tid < 128) {
    int e = s_sel[tid >> 1][tid & 1];
    atomicAdd(&s_hist[e], 1);
  }
  __syncthreads();

  if (tid < E_NUM) s_cursor[tid] = atomicAdd(&counts[tid], s_hist[tid]);
  __syncthreads();

  if (tid < 128) {
    int tl = tid >> 1, k = tid & 1;
    int e  = s_sel[tl][k];
    int pos = atomicAdd(&s_cursor[e], 1);
    perm[e * CAP + pos] = t0 + tl;
    wgt [e * CAP + pos] = s_w[tl][k];
  }
}

// ---- grouped expert GEMM: 256x256, BK=64, 8 waves, prefetch double-buffer,
//      FRAGMENT-ORDERED LDS (conflict-free lane-linear ds_read_b128).
// LDS 16B-slot ((rowgrp*2+kk)*64 + lane) holds A/B element
// (row = rowgrp*16 + (lane&15), k = kk*32 + (lane>>4)*8 .. +7).
// Staging thread (wid, lane), issue r: writes slot-block r*8+wid ->
// rowgrp = r*4 + (wid>>1), kk = wid&1; its global source row/col follow.
__global__ __launch_bounds__(512, 2) void moe_gemm(const __hip_bfloat16* __restrict__ xb,
                                                   const __hip_bfloat16* __restrict__ wb,
                                                   const float* __restrict__ be,
                                                   const int* __restrict__ counts,
                                                   const int* __restrict__ perm,
                                                   const float* __restrict__ wgt,
                                                   float* __restrict__ out) {
  int bid = blockIdx.x;
  int e  = bid >> 7;          // 128 blocks / expert
  int rt = (bid >> 2) & 31;
  int ct = bid & 3;
  int n = counts[e];
  if (n == 0 || rt * BM >= n) return;

  // [2 buffers][A: 32KB | B: 32KB], 128KB total
  __shared__ char lds[2 * 65536];

  int tid  = threadIdx.x;
  int lane = tid & 63;
  int wid  = tid >> 6;
  int wm = wid >> 2, wn = wid & 3;           // 2 x 4 wave grid, each 128x64 out

  const int*   permE = perm + e * CAP;
  const float* wgtE  = wgt  + e * CAP;

  // staging source geometry (fragment order)
  int rbase = ((wid >> 1) << 4) + (lane & 15);            // row within 64-row group
  int koff  = ((wid & 1) << 5) + ((lane >> 4) << 3);      // element offset in K-tile
  const __hip_bfloat16* gA[4];
  const __hip_bfloat16* gBp[4];
#pragma unroll
  for (int r = 0; r < 4; ++r) {
    int s = min(rt * BM + r * 64 + rbase, n - 1);
    gA[r]  = xb + (long)permE[s] * D_DIM + koff;
    gBp[r] = wb + ((long)e * O_DIM + ct * BN + r * 64 + rbase) * D_DIM + koff;
  }

  f32x4 acc[8][4];
#pragma unroll
  for (int m = 0; m < 8; ++m)
#pragma unroll
    for (int nn = 0; nn < 4; ++nn) acc[m][nn] = (f32x4){0.f, 0.f, 0.f, 0.f};

#define STAGE(buf, k0)                                                          \
  do {                                                                          \
    char* lA_ = lds + (buf) * 65536;                                            \
    char* lB_ = lds + (buf) * 65536 + 32768;                                    \
    _Pragma("unroll")                                                           \
    for (int r = 0; r < 4; ++r)                                                 \
      gld_lds16(gA[r] + (k0), lA_ + r * 8192 + wid * 1024);                     \
    _Pragma("unroll")                                                           \
    for (int r = 0; r < 4; ++r)                                                 \
      gld_lds16(gBp[r] + (k0), lB_ + r * 8192 + wid * 1024);                    \
  } while (0)

#define COMPUTE(buf)                                                            \
  do {                                                                          \
    const __hip_bfloat16* la_ = (const __hip_bfloat16*)(lds + (buf) * 65536);   \
    const __hip_bfloat16* lb_ = (const __hip_bfloat16*)(lds + (buf) * 65536 + 32768); \
    _Pragma("unroll")                                                           \
    for (int kk = 0; kk < 2; ++kk) {                                            \
      bf16x8 af[8], bfv[4];                                                     \
      _Pragma("unroll")                                                         \
      for (int m = 0; m < 8; ++m)                                               \
        af[m] = *(const bf16x8*)(la_ + ((wm * 8 + m) * 2 + kk) * 512 + lane * 8); \
      _Pragma("unroll")                                                         \
      for (int nn = 0; nn < 4; ++nn)                                            \
        bfv[nn] = *(const bf16x8*)(lb_ + ((wn * 4 + nn) * 2 + kk) * 512 + lane * 8); \
      _Pragma("unroll")                                                         \
      for (int m = 0; m < 8; ++m)                                               \
        _Pragma("unroll")                                                       \
        for (int nn = 0; nn < 4; ++nn)                                          \
          acc[m][nn] = __builtin_amdgcn_mfma_f32_16x16x32_bf16(af[m], bfv[nn],  \
                                                               acc[m][nn], 0, 0, 0); \
    }                                                                           \
  } while (0)

  // prologue: fill buffer 0, drain, barrier
  STAGE(0, 0);
  __syncthreads();

  int cur = 0;
  for (int kt = 0; kt < NT - 1; ++kt) {
    STAGE(cur ^ 1, (kt + 1) * BK);   // next-tile loads in flight across compute
    COMPUTE(cur);
    __syncthreads();                 // single vmcnt+lgkm drain per K-step
    cur ^= 1;
  }
  COMPUTE(cur);                      // last tile, no prefetch

  // epilogue: out[t, o] += w * (acc + be[e, o]) via fp32 atomics
  int base_m = rt * BM + wm * 128;
  int base_n = ct * BN + wn * 64;
  const float* beE = be + e * O_DIM;
#pragma unroll
  for (int m = 0; m < 8; ++m) {
#pragma unroll
    for (int r = 0; r < 4; ++r) {
      int s = base_m + m * 16 + (lane >> 4) * 4 + r;
      if (s < n) {
        long t  = permE[s];
        float w = wgtE[s];
        float* orow = out + t * O_DIM;
#pragma unroll
        for (int nn = 0; nn < 4; ++nn) {
          int o = base_n + nn * 16 + (lane & 15);
          atomicAdd(&orow[o], w * (acc[m][nn][r] + beE[o]));
        }
      }
    }
  }
#undef STAGE
#undef COMPUTE
}

extern "C" void kernel_launch(void* const* d_in, const int* in_sizes, int n_in,
                              void* d_out, int out_size, void* d_ws, size_t ws_size,
                              hipStream_t stream) {
  const float* x  = (const float*)d_in[0];   // [T, D]
  const float* Wg = (const float*)d_in[1];   // [E, D]
  const float* We = (const float*)d_in[2];   // [E, O, D]
  const float* be = (const float*)d_in[3];   // [E, O]
  float* out = (float*)d_out;                // [T, O]

  char* p = (char*)d_ws;
  __hip_bfloat16* xb = (__hip_bfloat16*)p;  p += (size_t)T_NUM * D_DIM * 2;
  __hip_bfloat16* wb = (__hip_bfloat16*)p;  p += (size_t)E_NUM * O_DIM * D_DIM * 2;
  int* counts = (int*)p;                    p += 256;
  int* perm   = (int*)p;                    p += (size_t)E_NUM * CAP * 4;
  float* wgt  = (float*)p;

  hipMemsetAsync(counts, 0, 256, stream);
  hipMemsetAsync(d_out, 0, (size_t)out_size * sizeof(float), stream);

  int n_w = E_NUM * O_DIM * D_DIM;  // 8388608
  cvt_kernel<<<n_w / 4 / 256, 256, 0, stream>>>(We, (ushort*)wb, n_w / 4);
  gate_kernel<<<T_NUM / 64, 256, 0, stream>>>(x, Wg, (ushort*)xb, counts, perm, wgt);
  moe_gemm<<<E_NUM * 32 * 4, 512, 0, stream>>>(xb, wb, be, counts, perm, wgt, out);
}

// Round 9
// 228.823 us; speedup vs baseline: 1.2573x; 1.2573x over previous
//
#include <hip/hip_runtime.h>
#include <hip/hip_bf16.h>

#define T_NUM 8192
#define D_DIM 1024
#define O_DIM 1024
#define E_NUM 8
#define CAP   8192
#define BM 256
#define BN 256
#define BK 64
#define NT (D_DIM / BK)   // 16 K-tiles

typedef float  f32x4  __attribute__((ext_vector_type(4)));
typedef __bf16 bf16x8 __attribute__((ext_vector_type(8)));

__device__ __forceinline__ void gld_lds16(const void* g, void* l) {
  __builtin_amdgcn_global_load_lds(
      (__attribute__((address_space(1))) void*)(void*)(g),
      (__attribute__((address_space(3))) void*)(l), 16, 0, 0);
}

__device__ __forceinline__ unsigned short f2bf(float f) {
  __hip_bfloat16 h = __float2bfloat16(f);
  return __builtin_bit_cast(unsigned short, h);
}

// ---------------- fp32 -> bf16 conversion (for We) ----------------
__global__ __launch_bounds__(256) void cvt_kernel(const float* __restrict__ in,
                                                  ushort* __restrict__ out, int n4) {
  int i = blockIdx.x * 256 + threadIdx.x;
  if (i >= n4) return;
  float4 v = ((const float4*)in)[i];
  ushort4 r;
  r.x = f2bf(v.x); r.y = f2bf(v.y); r.z = f2bf(v.z); r.w = f2bf(v.w);
  ((ushort4*)out)[i] = r;
}

// ---------------- gating ----------------
// perm entries are (token<<1)|slot ; per-token weights stored at wgt_tok[2t+slot].
__global__ __launch_bounds__(256) void gate_kernel(const float* __restrict__ x,
                                                   const float* __restrict__ Wg,
                                                   ushort* __restrict__ xb,
                                                   int* __restrict__ counts,
                                                   int* __restrict__ perm,
                                                   float* __restrict__ wgt_tok) {
  __shared__ int   s_sel[64][2];
  __shared__ int   s_hist[E_NUM];
  __shared__ int   s_cursor[E_NUM];

  int tid  = threadIdx.x;
  int lane = tid & 63;
  int wv   = tid >> 6;
  if (tid < E_NUM) s_hist[tid] = 0;

  int t0 = blockIdx.x * 64;

  for (int it = 0; it < 16; ++it) {
    int tl = wv * 16 + it;
    int t  = t0 + tl;
    const float4* xv = (const float4*)(x + (long)t * D_DIM);
    ushort4* xo = (ushort4*)(xb + (long)t * D_DIM);

    float acc[E_NUM];
#pragma unroll
    for (int e = 0; e < E_NUM; ++e) acc[e] = 0.f;

#pragma unroll
    for (int i = 0; i < 4; ++i) {
      float4 xf = xv[lane + i * 64];
      ushort4 r;
      r.x = f2bf(xf.x); r.y = f2bf(xf.y); r.z = f2bf(xf.z); r.w = f2bf(xf.w);
      xo[lane + i * 64] = r;
#pragma unroll
      for (int e = 0; e < E_NUM; ++e) {
        const float4* wv4 = (const float4*)(Wg + e * D_DIM);
        float4 wf = wv4[lane + i * 64];
        acc[e] += xf.x * wf.x + xf.y * wf.y + xf.z * wf.z + xf.w * wf.w;
      }
    }

    float logit[E_NUM];
#pragma unroll
    for (int e = 0; e < E_NUM; ++e) {
      float v = acc[e];
      for (int off = 32; off > 0; off >>= 1) v += __shfl_down(v, off);
      logit[e] = v;                      // valid on lane 0
    }

    if (lane == 0) {
      int e0 = 0; float v0 = logit[0];
#pragma unroll
      for (int e = 1; e < E_NUM; ++e)
        if (logit[e] > v0) { v0 = logit[e]; e0 = e; }  // strict > : lowest idx wins
      int e1 = -1; float v1 = -1e30f;
#pragma unroll
      for (int e = 0; e < E_NUM; ++e) {
        if (e == e0) continue;
        if (logit[e] > v1) { v1 = logit[e]; e1 = e; }
      }
      float ex  = expf(v1 - v0);
      float den = 1.f + ex;
      s_sel[tl][0] = e0;
      s_sel[tl][1] = e1;
      wgt_tok[2 * t + 0] = 1.f / den;
      wgt_tok[2 * t + 1] = ex / den;
    }
  }
  __syncthreads();

  if (tid < 128) {
    int e = s_sel[tid >> 1][tid & 1];
    atomicAdd(&s_hist[e], 1);
  }
  __syncthreads();

  if (tid < E_NUM) s_cursor[tid] = atomicAdd(&counts[tid], s_hist[tid]);
  __syncthreads();

  if (tid < 128) {
    int tl = tid >> 1, k = tid & 1;
    int e  = s_sel[tl][k];
    int pos = atomicAdd(&s_cursor[e], 1);
    perm[e * CAP + pos] = ((t0 + tl) << 1) | k;
  }
}

// ---- grouped expert GEMM: 256x256, BK=64, 8 waves, prefetch double-buffer,
//      fragment-ordered conflict-free LDS; plain bf16 partial stores.
__global__ __launch_bounds__(512, 2) void moe_gemm(const __hip_bfloat16* __restrict__ xb,
                                                   const __hip_bfloat16* __restrict__ wb,
                                                   const float* __restrict__ be,
                                                   const int* __restrict__ counts,
                                                   const int* __restrict__ perm,
                                                   ushort* __restrict__ partial) {
  int bid = blockIdx.x;
  int e  = bid >> 7;          // 128 blocks / expert
  int rt = (bid >> 2) & 31;
  int ct = bid & 3;
  int n = counts[e];
  if (n == 0 || rt * BM >= n) return;

  __shared__ char lds[2 * 65536];

  int tid  = threadIdx.x;
  int lane = tid & 63;
  int wid  = tid >> 6;
  int wm = wid >> 2, wn = wid & 3;           // 2 x 4 wave grid, each 128x64 out

  const int* permE = perm + e * CAP;

  // staging source geometry (fragment order; see round-7 notes)
  int rbase = ((wid >> 1) << 4) + (lane & 15);
  int koff  = ((wid & 1) << 5) + ((lane >> 4) << 3);
  const __hip_bfloat16* gA[4];
  const __hip_bfloat16* gBp[4];
#pragma unroll
  for (int r = 0; r < 4; ++r) {
    int s = min(rt * BM + r * 64 + rbase, n - 1);
    gA[r]  = xb + (long)(permE[s] >> 1) * D_DIM + koff;
    gBp[r] = wb + ((long)e * O_DIM + ct * BN + r * 64 + rbase) * D_DIM + koff;
  }

  f32x4 acc[8][4];
#pragma unroll
  for (int m = 0; m < 8; ++m)
#pragma unroll
    for (int nn = 0; nn < 4; ++nn) acc[m][nn] = (f32x4){0.f, 0.f, 0.f, 0.f};

#define STAGE(buf, k0)                                                          \
  do {                                                                          \
    char* lA_ = lds + (buf) * 65536;                                            \
    char* lB_ = lds + (buf) * 65536 + 32768;                                    \
    _Pragma("unroll")                                                           \
    for (int r = 0; r < 4; ++r)                                                 \
      gld_lds16(gA[r] + (k0), lA_ + r * 8192 + wid * 1024);                     \
    _Pragma("unroll")                                                           \
    for (int r = 0; r < 4; ++r)                                                 \
      gld_lds16(gBp[r] + (k0), lB_ + r * 8192 + wid * 1024);                    \
  } while (0)

#define COMPUTE(buf)                                                            \
  do {                                                                          \
    const __hip_bfloat16* la_ = (const __hip_bfloat16*)(lds + (buf) * 65536);   \
    const __hip_bfloat16* lb_ = (const __hip_bfloat16*)(lds + (buf) * 65536 + 32768); \
    _Pragma("unroll")                                                           \
    for (int kk = 0; kk < 2; ++kk) {                                            \
      bf16x8 af[8], bfv[4];                                                     \
      _Pragma("unroll")                                                         \
      for (int m = 0; m < 8; ++m)                                               \
        af[m] = *(const bf16x8*)(la_ + ((wm * 8 + m) * 2 + kk) * 512 + lane * 8); \
      _Pragma("unroll")                                                         \
      for (int nn = 0; nn < 4; ++nn)                                            \
        bfv[nn] = *(const bf16x8*)(lb_ + ((wn * 4 + nn) * 2 + kk) * 512 + lane * 8); \
      _Pragma("unroll")                                                         \
      for (int m = 0; m < 8; ++m)                                               \
        _Pragma("unroll")                                                       \
        for (int nn = 0; nn < 4; ++nn)                                          \
          acc[m][nn] = __builtin_amdgcn_mfma_f32_16x16x32_bf16(af[m], bfv[nn],  \
                                                               acc[m][nn], 0, 0, 0); \
    }                                                                           \
  } while (0)

  STAGE(0, 0);
  __syncthreads();

  int cur = 0;
  for (int kt = 0; kt < NT - 1; ++kt) {
    STAGE(cur ^ 1, (kt + 1) * BK);
    COMPUTE(cur);
    __syncthreads();
    cur ^= 1;
  }
  COMPUTE(cur);

  // epilogue: partial[entry][o] = bf16(acc + be[e,o])  (plain stores, no atomics)
  int base_m = rt * BM + wm * 128;
  int base_n = ct * BN + wn * 64;
  const float* beE = be + e * O_DIM;
#pragma unroll
  for (int m = 0; m < 8; ++m) {
#pragma unroll
    for (int r = 0; r < 4; ++r) {
      int s = base_m + m * 16 + (lane >> 4) * 4 + r;
      if (s < n) {
        long entry = permE[s];
        ushort* prow = partial + entry * O_DIM;
#pragma unroll
        for (int nn = 0; nn < 4; ++nn) {
          int o = base_n + nn * 16 + (lane & 15);
          prow[o] = f2bf(acc[m][nn][r] + beE[o]);
        }
      }
    }
  }
#undef STAGE
#undef COMPUTE
}

// ---------------- combine: out[t] = w0*p[2t] + w1*p[2t+1] ----------------
__global__ __launch_bounds__(256) void combine_kernel(const ushort* __restrict__ partial,
                                                      const float* __restrict__ wgt_tok,
                                                      float* __restrict__ out) {
  long i = (long)blockIdx.x * 256 + threadIdx.x;   // [0, T*O/8)
  int t = (int)(i >> 7);
  int g = (int)(i & 127);
  float w0 = wgt_tok[2 * t + 0];
  float w1 = wgt_tok[2 * t + 1];
  const uint4* p0 = (const uint4*)(partial + (long)(2 * t)     * O_DIM);
  const uint4* p1 = (const uint4*)(partial + (long)(2 * t + 1) * O_DIM);
  uint4 a = p0[g];
  uint4 b = p1[g];
  float4 o0, o1;
  uint ua[4] = {a.x, a.y, a.z, a.w};
  uint ub[4] = {b.x, b.y, b.z, b.w};
  float res[8];
#pragma unroll
  for (int j = 0; j < 4; ++j) {
    float a_lo = __builtin_bit_cast(float, ua[j] << 16);
    float a_hi = __builtin_bit_cast(float, ua[j] & 0xFFFF0000u);
    float b_lo = __builtin_bit_cast(float, ub[j] << 16);
    float b_hi = __builtin_bit_cast(float, ub[j] & 0xFFFF0000u);
    res[2 * j + 0] = w0 * a_lo + w1 * b_lo;
    res[2 * j + 1] = w0 * a_hi + w1 * b_hi;
  }
  o0 = (float4){res[0], res[1], res[2], res[3]};
  o1 = (float4){res[4], res[5], res[6], res[7]};
  float4* orow = (float4*)(out + (long)t * O_DIM + g * 8);
  orow[0] = o0;
  orow[1] = o1;
}

extern "C" void kernel_launch(void* const* d_in, const int* in_sizes, int n_in,
                              void* d_out, int out_size, void* d_ws, size_t ws_size,
                              hipStream_t stream) {
  const float* x  = (const float*)d_in[0];   // [T, D]
  const float* Wg = (const float*)d_in[1];   // [E, D]
  const float* We = (const float*)d_in[2];   // [E, O, D]
  const float* be = (const float*)d_in[3];   // [E, O]
  float* out = (float*)d_out;                // [T, O]

  char* p = (char*)d_ws;
  __hip_bfloat16* xb = (__hip_bfloat16*)p;  p += (size_t)T_NUM * D_DIM * 2;       // 16MB
  __hip_bfloat16* wb = (__hip_bfloat16*)p;  p += (size_t)E_NUM * O_DIM * D_DIM * 2; // 16MB
  int* counts = (int*)p;                    p += 256;
  int* perm   = (int*)p;                    p += (size_t)E_NUM * CAP * 4;          // 256KB
  float* wgt_tok = (float*)p;               p += (size_t)T_NUM * 2 * 4;            // 64KB
  ushort* partial = (ushort*)p;             // [T*2][O] bf16 = 32MB

  hipMemsetAsync(counts, 0, 256, stream);

  int n_w = E_NUM * O_DIM * D_DIM;  // 8388608
  cvt_kernel<<<n_w / 4 / 256, 256, 0, stream>>>(We, (ushort*)wb, n_w / 4);
  gate_kernel<<<T_NUM / 64, 256, 0, stream>>>(x, Wg, (ushort*)xb, counts, perm, wgt_tok);
  moe_gemm<<<E_NUM * 32 * 4, 512, 0, stream>>>(xb, wb, be, counts, perm, partial);
  combine_kernel<<<(T_NUM * O_DIM / 8) / 256, 256, 0, stream>>>(partial, wgt_tok, out);
}

// Round 10
// 221.222 us; speedup vs baseline: 1.3005x; 1.0344x over previous
//
#include <hip/hip_runtime.h>
#include <hip/hip_bf16.h>

#define T_NUM 8192
#define D_DIM 1024
#define O_DIM 1024
#define E_NUM 8
#define CAP   8192
#define BM 256
#define BN 256
#define BK 64
#define NT (D_DIM / BK)   // 16 K-tiles, processed 2/iteration

typedef float  f32x4  __attribute__((ext_vector_type(4)));
typedef __bf16 bf16x8 __attribute__((ext_vector_type(8)));

__device__ __forceinline__ void gld_lds16(const void* g, void* l) {
  __builtin_amdgcn_global_load_lds(
      (__attribute__((address_space(1))) void*)(void*)(g),
      (__attribute__((address_space(3))) void*)(l), 16, 0, 0);
}

__device__ __forceinline__ unsigned short f2bf(float f) {
  __hip_bfloat16 h = __float2bfloat16(f);
  return __builtin_bit_cast(unsigned short, h);
}

// ---------------- fp32 -> bf16 conversion (for We) ----------------
__global__ __launch_bounds__(256) void cvt_kernel(const float* __restrict__ in,
                                                  ushort* __restrict__ out, int n4) {
  int i = blockIdx.x * 256 + threadIdx.x;
  if (i >= n4) return;
  float4 v = ((const float4*)in)[i];
  ushort4 r;
  r.x = f2bf(v.x); r.y = f2bf(v.y); r.z = f2bf(v.z); r.w = f2bf(v.w);
  ((ushort4*)out)[i] = r;
}

// ---------------- gating ----------------
__global__ __launch_bounds__(256) void gate_kernel(const float* __restrict__ x,
                                                   const float* __restrict__ Wg,
                                                   ushort* __restrict__ xb,
                                                   int* __restrict__ counts,
                                                   int* __restrict__ perm,
                                                   float* __restrict__ wgt_tok) {
  __shared__ int s_sel[64][2];
  __shared__ int s_hist[E_NUM];
  __shared__ int s_cursor[E_NUM];

  int tid  = threadIdx.x;
  int lane = tid & 63;
  int wv   = tid >> 6;
  if (tid < E_NUM) s_hist[tid] = 0;

  int t0 = blockIdx.x * 64;

  for (int it = 0; it < 16; ++it) {
    int tl = wv * 16 + it;
    int t  = t0 + tl;
    const float4* xv = (const float4*)(x + (long)t * D_DIM);
    ushort4* xo = (ushort4*)(xb + (long)t * D_DIM);

    float acc[E_NUM];
#pragma unroll
    for (int e = 0; e < E_NUM; ++e) acc[e] = 0.f;

#pragma unroll
    for (int i = 0; i < 4; ++i) {
      float4 xf = xv[lane + i * 64];
      ushort4 r;
      r.x = f2bf(xf.x); r.y = f2bf(xf.y); r.z = f2bf(xf.z); r.w = f2bf(xf.w);
      xo[lane + i * 64] = r;
#pragma unroll
      for (int e = 0; e < E_NUM; ++e) {
        const float4* wv4 = (const float4*)(Wg + e * D_DIM);
        float4 wf = wv4[lane + i * 64];
        acc[e] += xf.x * wf.x + xf.y * wf.y + xf.z * wf.z + xf.w * wf.w;
      }
    }

    float logit[E_NUM];
#pragma unroll
    for (int e = 0; e < E_NUM; ++e) {
      float v = acc[e];
      for (int off = 32; off > 0; off >>= 1) v += __shfl_down(v, off);
      logit[e] = v;
    }

    if (lane == 0) {
      int e0 = 0; float v0 = logit[0];
#pragma unroll
      for (int e = 1; e < E_NUM; ++e)
        if (logit[e] > v0) { v0 = logit[e]; e0 = e; }
      int e1 = -1; float v1 = -1e30f;
#pragma unroll
      for (int e = 0; e < E_NUM; ++e) {
        if (e == e0) continue;
        if (logit[e] > v1) { v1 = logit[e]; e1 = e; }
      }
      float ex  = expf(v1 - v0);
      float den = 1.f + ex;
      s_sel[tl][0] = e0;
      s_sel[tl][1] = e1;
      wgt_tok[2 * t + 0] = 1.f / den;
      wgt_tok[2 * t + 1] = ex / den;
    }
  }
  __syncthreads();

  if (tid < 128) {
    int e = s_sel[tid >> 1][tid & 1];
    atomicAdd(&s_hist[e], 1);
  }
  __syncthreads();

  if (tid < E_NUM) s_cursor[tid] = atomicAdd(&counts[tid], s_hist[tid]);
  __syncthreads();

  if (tid < 128) {
    int tl = tid >> 1, k = tid & 1;
    int e  = s_sel[tl][k];
    int pos = atomicAdd(&s_cursor[e], 1);
    perm[e * CAP + pos] = ((t0 + tl) << 1) | k;
  }
}

// ---- grouped expert GEMM: 256x256, BK=64, 8 waves, 8-PHASE counted-vmcnt
// schedule (T3+T4+T5). Fragment-ordered conflict-free LDS (reads are
// uniform-base + lane*16). Per phase: 12 ds_read_b128 + 1 half-tile stage
// (2 gld_lds16) + barrier + setprio(1) + 16 MFMA + setprio(0) + barrier.
// vmcnt(4) only at phases 4/8: retires the tile read in the next 4 phases
// (ledger: 12 outstanding -> retire 8 = that tile, 4 left in flight).
// Stage order (A1[t+1],B1[t+1],A0[t+2],B0[t+2],A1[t+2],B1[t+2],A0[t+3],
// B0[t+3]) lands every write >=1 barrier after its region's last read.
__global__ __launch_bounds__(512, 2) void moe_gemm(const __hip_bfloat16* __restrict__ xb,
                                                   const __hip_bfloat16* __restrict__ wb,
                                                   const float* __restrict__ be,
                                                   const int* __restrict__ counts,
                                                   const int* __restrict__ perm,
                                                   ushort* __restrict__ partial) {
  int bid = blockIdx.x;
  int e  = bid >> 7;
  int rt = (bid >> 2) & 31;
  int ct = bid & 3;
  int n = counts[e];
  if (n == 0 || rt * BM >= n) return;

  __shared__ char lds[2 * 65536];   // dbuf d: [A 32KB | B 32KB]; tile t -> dbuf t&1

  int tid  = threadIdx.x;
  int lane = tid & 63;
  int wid  = tid >> 6;
  int wm = wid >> 2, wn = wid & 3;

  const int* permE = perm + e * CAP;

  // ---- A staging sources (unchanged fragment order): call r in 0..3 writes
  // slabs s=r*8+wid; element (row = r*64 + (wid>>1)*16 + (lane&15),
  // k = (wid&1)*32 + (lane>>4)*8). A-half mh = calls {mh, mh+2}.
  int arow_in = (wid >> 1) * 16 + (lane & 15);
  int akoff   = ((wid & 1) << 5) + ((lane >> 4) << 3);
  const __hip_bfloat16* gA[4];
#pragma unroll
  for (int r = 0; r < 4; ++r) {
    int s = min(rt * BM + r * 64 + arow_in, n - 1);
    gA[r] = xb + (long)(permE[s] >> 1) * D_DIM + akoff;
  }

  // ---- B staging sources: slab s = nh*16 + wn*4 + nl*2 + kk (phase-contig).
  // Call (nh,p): s = nh*16+p*8+wid -> nn = (p*2 + (wid>>2))*4 + nh*2 + ((wid>>1)&1),
  // kk = wid&1. Row = nn*16 + (lane&15).
  const __hip_bfloat16* gB[4];   // [nh*2+p]
#pragma unroll
  for (int nh = 0; nh < 2; ++nh)
#pragma unroll
    for (int p = 0; p < 2; ++p) {
      int nn = (p * 2 + (wid >> 2)) * 4 + nh * 2 + ((wid >> 1) & 1);
      gB[nh * 2 + p] = wb + ((long)e * O_DIM + ct * BN + nn * 16 + (lane & 15)) * D_DIM
                       + ((wid & 1) << 5) + ((lane >> 4) << 3);
    }

  f32x4 acc[8][4];
#pragma unroll
  for (int m = 0; m < 8; ++m)
#pragma unroll
    for (int nn = 0; nn < 4; ++nn) acc[m][nn] = (f32x4){0.f, 0.f, 0.f, 0.f};

#define SA(buf, r, k0)  gld_lds16(gA[r] + (k0), lds + (buf) * 65536 + (r) * 8192 + wid * 1024)
#define SB(buf, nh, p, k0) gld_lds16(gB[(nh) * 2 + (p)] + (k0), \
    lds + (buf) * 65536 + 32768 + ((nh) * 16 + (p) * 8 + wid) * 1024)
#define STAGE_AH(buf, mh, k0) do { SA(buf, (mh), k0); SA(buf, (mh) + 2, k0); } while (0)
#define STAGE_BH(buf, nh, k0) do { SB(buf, (nh), 0, k0); SB(buf, (nh), 1, k0); } while (0)
#define VMCNT4 asm volatile("s_waitcnt vmcnt(4)" ::: "memory")
#define VMCNT0 asm volatile("s_waitcnt vmcnt(0)" ::: "memory")
#define NOPST  ((void)0)

#define PHASE(buf, mh, nh, WCNT, ...)                                            \
  do {                                                                           \
    const __hip_bfloat16* la_ = (const __hip_bfloat16*)(lds + (buf) * 65536);    \
    const __hip_bfloat16* lb_ = (const __hip_bfloat16*)(lds + (buf) * 65536 + 32768); \
    bf16x8 af[4][2], bv[2][2];                                                   \
    _Pragma("unroll")                                                            \
    for (int i = 0; i < 4; ++i)                                                  \
      _Pragma("unroll")                                                          \
      for (int kk = 0; kk < 2; ++kk)                                             \
        af[i][kk] = *(const bf16x8*)(la_ + ((wm * 8 + (mh) * 4 + i) * 2 + kk) * 512 + lane * 8); \
    _Pragma("unroll")                                                            \
    for (int nl = 0; nl < 2; ++nl)                                               \
      _Pragma("unroll")                                                          \
      for (int kk = 0; kk < 2; ++kk)                                             \
        bv[nl][kk] = *(const bf16x8*)(lb_ + ((nh) * 16 + wn * 4 + nl * 2 + kk) * 512 + lane * 8); \
    __VA_ARGS__;                                                                 \
    WCNT;                                                                        \
    __builtin_amdgcn_s_barrier();                                                \
    __builtin_amdgcn_s_setprio(1);                                               \
    _Pragma("unroll")                                                            \
    for (int i = 0; i < 4; ++i)                                                  \
      _Pragma("unroll")                                                          \
      for (int nl = 0; nl < 2; ++nl)                                             \
        _Pragma("unroll")                                                        \
        for (int kk = 0; kk < 2; ++kk)                                           \
          acc[(mh) * 4 + i][(nh) * 2 + nl] = __builtin_amdgcn_mfma_f32_16x16x32_bf16( \
              af[i][kk], bv[nl][kk], acc[(mh) * 4 + i][(nh) * 2 + nl], 0, 0, 0); \
    __builtin_amdgcn_s_setprio(0);                                               \
    __builtin_amdgcn_s_barrier();                                                \
  } while (0)

  // ---- prologue: tile 0 full + A0,B0 of tile 1; wait tile 0 (4 left in flight)
  STAGE_AH(0, 0, 0);  STAGE_BH(0, 0, 0);
  STAGE_AH(0, 1, 0);  STAGE_BH(0, 1, 0);
  STAGE_AH(1, 0, BK); STAGE_BH(1, 0, BK);
  VMCNT4;
  __builtin_amdgcn_s_barrier();

  // ---- main: iterations j=0..6, tiles 2j (dbuf0) and 2j+1 (dbuf1)
  for (int j = 0; j < 7; ++j) {
    int kA = (2 * j + 1) * BK;   // tile 2j+1 (finish halves A1,B1)
    int kB = (2 * j + 2) * BK;   // tile 2j+2
    int kC = (2 * j + 3) * BK;   // tile 2j+3 (first halves A0,B0)
    PHASE(0, 0, 0, NOPST,  STAGE_AH(1, 1, kA));
    PHASE(0, 0, 1, NOPST,  STAGE_BH(1, 1, kA));
    PHASE(0, 1, 0, NOPST,  STAGE_AH(0, 0, kB));
    PHASE(0, 1, 1, VMCNT4, STAGE_BH(0, 0, kB));
    PHASE(1, 0, 0, NOPST,  STAGE_AH(0, 1, kB));
    PHASE(1, 0, 1, NOPST,  STAGE_BH(0, 1, kB));
    PHASE(1, 1, 0, NOPST,  STAGE_AH(1, 0, kC));
    PHASE(1, 1, 1, VMCNT4, STAGE_BH(1, 0, kC));
  }
  // ---- epilogue iteration: tiles 14, 15 (stage only A1,B1 of 15)
  {
    int kA = 15 * BK;
    PHASE(0, 0, 0, NOPST,  STAGE_AH(1, 1, kA));
    PHASE(0, 0, 1, NOPST,  STAGE_BH(1, 1, kA));
    PHASE(0, 1, 0, NOPST,  NOPST);
    PHASE(0, 1, 1, VMCNT0, NOPST);
    PHASE(1, 0, 0, NOPST,  NOPST);
    PHASE(1, 0, 1, NOPST,  NOPST);
    PHASE(1, 1, 0, NOPST,  NOPST);
    PHASE(1, 1, 1, NOPST,  NOPST);
  }

  // ---- C-write: bf16 partials, plain stores
  int base_m = rt * BM + wm * 128;
  int base_n = ct * BN + wn * 64;
  const float* beE = be + e * O_DIM;
#pragma unroll
  for (int m = 0; m < 8; ++m) {
#pragma unroll
    for (int r = 0; r < 4; ++r) {
      int s = base_m + m * 16 + (lane >> 4) * 4 + r;
      if (s < n) {
        long entry = permE[s];
        ushort* prow = partial + entry * O_DIM;
#pragma unroll
        for (int nn = 0; nn < 4; ++nn) {
          int o = base_n + nn * 16 + (lane & 15);
          prow[o] = f2bf(acc[m][nn][r] + beE[o]);
        }
      }
    }
  }
#undef SA
#undef SB
#undef STAGE_AH
#undef STAGE_BH
#undef PHASE
}

// ---------------- combine: out[t] = w0*p[2t] + w1*p[2t+1] ----------------
__global__ __launch_bounds__(256) void combine_kernel(const ushort* __restrict__ partial,
                                                      const float* __restrict__ wgt_tok,
                                                      float* __restrict__ out) {
  long i = (long)blockIdx.x * 256 + threadIdx.x;
  int t = (int)(i >> 7);
  int g = (int)(i & 127);
  float w0 = wgt_tok[2 * t + 0];
  float w1 = wgt_tok[2 * t + 1];
  const uint4* p0 = (const uint4*)(partial + (long)(2 * t)     * O_DIM);
  const uint4* p1 = (const uint4*)(partial + (long)(2 * t + 1) * O_DIM);
  uint4 a = p0[g];
  uint4 b = p1[g];
  uint ua[4] = {a.x, a.y, a.z, a.w};
  uint ub[4] = {b.x, b.y, b.z, b.w};
  float res[8];
#pragma unroll
  for (int j = 0; j < 4; ++j) {
    float a_lo = __builtin_bit_cast(float, ua[j] << 16);
    float a_hi = __builtin_bit_cast(float, ua[j] & 0xFFFF0000u);
    float b_lo = __builtin_bit_cast(float, ub[j] << 16);
    float b_hi = __builtin_bit_cast(float, ub[j] & 0xFFFF0000u);
    res[2 * j + 0] = w0 * a_lo + w1 * b_lo;
    res[2 * j + 1] = w0 * a_hi + w1 * b_hi;
  }
  float4* orow = (float4*)(out + (long)t * O_DIM + g * 8);
  orow[0] = (float4){res[0], res[1], res[2], res[3]};
  orow[1] = (float4){res[4], res[5], res[6], res[7]};
}

extern "C" void kernel_launch(void* const* d_in, const int* in_sizes, int n_in,
                              void* d_out, int out_size, void* d_ws, size_t ws_size,
                              hipStream_t stream) {
  const float* x  = (const float*)d_in[0];
  const float* Wg = (const float*)d_in[1];
  const float* We = (const float*)d_in[2];
  const float* be = (const float*)d_in[3];
  float* out = (float*)d_out;

  char* p = (char*)d_ws;
  __hip_bfloat16* xb = (__hip_bfloat16*)p;  p += (size_t)T_NUM * D_DIM * 2;
  __hip_bfloat16* wb = (__hip_bfloat16*)p;  p += (size_t)E_NUM * O_DIM * D_DIM * 2;
  int* counts = (int*)p;                    p += 256;
  int* perm   = (int*)p;                    p += (size_t)E_NUM * CAP * 4;
  float* wgt_tok = (float*)p;               p += (size_t)T_NUM * 2 * 4;
  ushort* partial = (ushort*)p;             // [T*2][O] bf16 = 32MB

  hipMemsetAsync(counts, 0, 256, stream);

  int n_w = E_NUM * O_DIM * D_DIM;
  cvt_kernel<<<n_w / 4 / 256, 256, 0, stream>>>(We, (ushort*)wb, n_w / 4);
  gate_kernel<<<T_NUM / 64, 256, 0, stream>>>(x, Wg, (ushort*)xb, counts, perm, wgt_tok);
  moe_gemm<<<E_NUM * 32 * 4, 512, 0, stream>>>(xb, wb, be, counts, perm, partial);
  combine_kernel<<<(T_NUM * O_DIM / 8) / 256, 256, 0, stream>>>(partial, wgt_tok, out);
}